// Round 1
// 285.651 us; speedup vs baseline: 1.0033x; 1.0033x over previous
//
#include <hip/hip_runtime.h>

#define BB 512
#define CC 6
#define TT 77
#define DD 512
#define LIMG 193

// Grid: 1024 blocks = (b, half-of-D). Block: 512 threads = 8 waves.
//   half = blockIdx.x & 1 : which 64-float4 half of D this block owns
//   colL = tid >> 3       : float4 column within the half (0..63)
//   q    = tid & 7        : T-stripe (t = q, q+8, ...) -- lives in the LANE,
//                           so the cross-stripe sum is an in-wave shfl reduce.
// No LDS partial buffer, single barrier, 2.5 KB LDS -> 4 blocks/CU co-resident
// (32 waves/CU vs 16 before). __launch_bounds__(512,8) caps VGPR at 64 for that.
__global__ __launch_bounds__(512, 8) void clip_fused(
    const float* __restrict__ img,
    const float* __restrict__ txt,
    const float* __restrict__ ls,
    const int* __restrict__ cap,
    const int* __restrict__ mask,
    float* __restrict__ out)
{
    const int bid  = blockIdx.x;
    const int b    = bid >> 1;
    const int half = bid & 1;
    const int tid  = threadIdx.x;
    const int q    = tid & 7;
    const int colL = tid >> 3;            // 0..63
    const int col  = (half << 6) + colL;  // float4 column of D (0..127)

    __shared__ float mT[TT * 8];   // mask transposed + padded: mT[t*8 + c], 2464 B
    __shared__ int   wred[2];

    // ---- stage mask as float, transposed, in LDS ----
    const int* mrow = mask + (size_t)b * (CC * TT);
    for (int i = tid; i < TT * 8; i += 512) {
        const int c = i & 7;
        const int t = i >> 3;
        mT[i] = (c < CC) ? (float)mrow[c * TT + t] : 0.0f;
    }

    // ---- argmax(captions[b,:]) with first-index tie-break (half 0 only) ----
    // key = (value << 8) | (255 - t): max over keys -> max value, smallest t wins.
    if (half == 0) {
        const int* crow = cap + (size_t)b * TT;
        int key = -1;
        if (tid < TT) key = (crow[tid] << 8) | (255 - tid);
        if (tid < 128) {
            #pragma unroll
            for (int off = 32; off; off >>= 1) key = max(key, __shfl_down(key, off));
            if ((tid & 63) == 0) wred[tid >> 6] = key;
        }
    }
    __syncthreads();

    const float4* trow = (const float4*)(txt + (size_t)b * (TT * DD));

    // ---- global_text (half 0) / global_image (half 1) copies ----
    if (half == 0) {
        if (tid < 128) {
            const int eot = 255 - (max(wred[0], wred[1]) & 255);
            ((float4*)out)[(size_t)b * 128 + tid] = trow[(size_t)eot * 128 + tid];
        }
    } else {
        if (tid < 128) {
            const float4* irow = (const float4*)(img + (size_t)b * (LIMG * DD));
            ((float4*)(out + (size_t)BB * DD))[(size_t)b * 128 + tid] = irow[tid];
        }
    }

    // ---- masked T-sum, stripe q in lane ----
    float4 acc[CC];
    #pragma unroll
    for (int c = 0; c < CC; c++) acc[c] = make_float4(0.f, 0.f, 0.f, 0.f);

    #pragma unroll 2
    for (int t = q; t < TT; t += 8) {
        const float4 v   = trow[(size_t)t * 128 + col];
        const float4 m03 = *(const float4*)&mT[t * 8];       // 32-B aligned
        const float2 m45 = *(const float2*)&mT[t * 8 + 4];
        const float mw[CC] = { m03.x, m03.y, m03.z, m03.w, m45.x, m45.y };
        #pragma unroll
        for (int c = 0; c < CC; c++) {
            acc[c].x += mw[c] * v.x;
            acc[c].y += mw[c] * v.y;
            acc[c].z += mw[c] * v.z;
            acc[c].w += mw[c] * v.w;
        }
    }

    // ---- reduce the 8 T-stripes inside each 8-lane group ----
    #pragma unroll
    for (int off = 4; off; off >>= 1) {
        #pragma unroll
        for (int c = 0; c < CC; c++) {
            acc[c].x += __shfl_down(acc[c].x, off);
            acc[c].y += __shfl_down(acc[c].y, off);
            acc[c].z += __shfl_down(acc[c].z, off);
            acc[c].w += __shfl_down(acc[c].w, off);
        }
    }

    // q==0 lanes of a wave hold cols 8w..8w+7 -> each wave's 8 stores per c
    // coalesce into one contiguous 128-B line.
    if (q == 0) {
        float4* out_lt = (float4*)(out + 2 * (size_t)BB * DD);
        const float inv = 1.0f / (float)TT;
        #pragma unroll
        for (int c = 0; c < CC; c++) {
            float4 r;
            r.x = acc[c].x * inv;
            r.y = acc[c].y * inv;
            r.z = acc[c].z * inv;
            r.w = acc[c].w * inv;
            out_lt[((size_t)b * CC + c) * 128 + col] = r;
        }
    }

    // ---- logit_scale passthrough ----
    if (bid == 0 && tid == 0)
        out[(size_t)2 * BB * DD + (size_t)BB * CC * DD] = ls[0];
}

extern "C" void kernel_launch(void* const* d_in, const int* in_sizes, int n_in,
                              void* d_out, int out_size, void* d_ws, size_t ws_size,
                              hipStream_t stream) {
    const float* img  = (const float*)d_in[0];  // (B, LI, D) f32
    const float* txt  = (const float*)d_in[1];  // (B, T, D)  f32
    const float* ls   = (const float*)d_in[2];  // (1,)       f32
    const int*   cap  = (const int*)d_in[3];    // (B, T)     i32
    const int*   mask = (const int*)d_in[4];    // (B, C, T)  i32
    float* out = (float*)d_out;

    clip_fused<<<dim3(2 * BB), dim3(512), 0, stream>>>(img, txt, ls, cap, mask, out);
}